// Round 6
// baseline (108.946 us; speedup 1.0000x reference)
//
#include <hip/hip_runtime.h>
#include <math.h>

#define NTOK 16384
#define DDIM 4096
#define NEXP 64
#define TAU  2e-4f
#define WS_LO 262144   // short-offset of lo-plane inside d_ws
#define KSTEP 256      // floats of K per staged tile (1 KiB per row)
#define NSTEP (DDIM / KSTEP)   // 16

typedef short bf16x8 __attribute__((ext_vector_type(8)));
typedef float f32x4  __attribute__((ext_vector_type(4)));

__device__ __forceinline__ unsigned short bf16_rne(float f) {
  unsigned u = __float_as_uint(f);
  u += 0x7fffu + ((u >> 16) & 1u);
  return (unsigned short)(u >> 16);
}

__device__ __forceinline__ void split4(float4 v, uint2& hi, uint2& lo) {
  unsigned h0 = bf16_rne(v.x), h1 = bf16_rne(v.y), h2 = bf16_rne(v.z), h3 = bf16_rne(v.w);
  float r0 = v.x - __uint_as_float(h0 << 16);
  float r1 = v.y - __uint_as_float(h1 << 16);
  float r2 = v.z - __uint_as_float(h2 << 16);
  float r3 = v.w - __uint_as_float(h3 << 16);
  unsigned l0 = bf16_rne(r0), l1 = bf16_rne(r1), l2 = bf16_rne(r2), l3 = bf16_rne(r3);
  hi = make_uint2(h0 | (h1 << 16), h2 | (h3 << 16));
  lo = make_uint2(l0 | (l1 << 16), l2 | (l3 << 16));
}

__device__ __forceinline__ bf16x8 mk8(uint2 a, uint2 b) {
  union { uint4 u; bf16x8 v; } t;
  t.u = make_uint4(a.x, a.y, b.x, b.y);
  return t.v;
}

__device__ __forceinline__ void gld_lds16(const float* g, char* l) {
  __builtin_amdgcn_global_load_lds((const __attribute__((address_space(1))) void*)g,
                                   (__attribute__((address_space(3))) void*)l,
                                   16, 0, 0);
}

__device__ __forceinline__ bool better(float va, int ia, float vb, int ib) {
  return (va > vb) || (va == vb && ia < ib);
}
__device__ __forceinline__ bool betterd(double va, int ia, double vb, int ib) {
  return (va > vb) || (va == vb && ia < ib);
}
#define CE(va, ia, vb, ib) { if (better(vb, ib, va, ia)) { float _tv = va; va = vb; vb = _tv; int _ti = ia; ia = ib; ib = _ti; } }

// ---- kernel 1: split W (fp32) into bf16 hi/lo, MFMA-fragment-linear, once ----
// reader (32k-chunk cc, group g, lane l): W[g*16+(l&15)][cc*32+(l>>4)*8+j]
// hi short-offset: cc*2048 + g*512 + l*8 ; lo at +WS_LO
__global__ __launch_bounds__(256)
void presplit_w(const float* __restrict__ w, short* __restrict__ ws) {
  const int tid = blockIdx.x * 256 + threadIdx.x;  // 32768 threads
  const int e = tid >> 9;          // expert 0..63
  const int o = tid & 511;         // k-octet 0..511
  const int c = o >> 2, q = o & 3;
  const int l = (e & 15) + 16 * q;
  const int g = e >> 4;
  const float* src = w + (size_t)e * DDIM + o * 8;
  float4 v0 = *(const float4*)src;
  float4 v1 = *(const float4*)(src + 4);
  uint2 h0, s0, h1, s1;
  split4(v0, h0, s0);
  split4(v1, h1, s1);
  const int off = c * 2048 + g * 512 + l * 8;
  *(uint4*)(ws + off)         = make_uint4(h0.x, h0.y, h1.x, h1.y);
  *(uint4*)(ws + WS_LO + off) = make_uint4(s0.x, s0.y, s1.x, s1.y);
}

// ---- fp64 recompute for near-tie tokens (rare); executed by one full wave ----
__device__ __noinline__ void fixup_token(const float* __restrict__ x,
                                         const float* __restrict__ wgt,
                                         float* __restrict__ out_idx,
                                         float* __restrict__ out_wt,
                                         int tok, unsigned pk, int l) {
  const int e0 = pk & 255, e1 = (pk >> 8) & 255, e2 = (pk >> 16) & 255, e3 = (pk >> 24) & 255;
  const float* xr = x   + (size_t)tok * DDIM + l * 64;
  const float* w0 = wgt + (size_t)e0 * DDIM + l * 64;
  const float* w1 = wgt + (size_t)e1 * DDIM + l * 64;
  const float* w2 = wgt + (size_t)e2 * DDIM + l * 64;
  const float* w3 = wgt + (size_t)e3 * DDIM + l * 64;
  double s0 = 0.0, s1 = 0.0, s2 = 0.0, s3 = 0.0;
#pragma unroll 4
  for (int j = 0; j < 64; j += 4) {
    float4 xv = *(const float4*)(xr + j);
    float4 av = *(const float4*)(w0 + j);
    s0 = fma((double)xv.x, (double)av.x, s0); s0 = fma((double)xv.y, (double)av.y, s0);
    s0 = fma((double)xv.z, (double)av.z, s0); s0 = fma((double)xv.w, (double)av.w, s0);
    av = *(const float4*)(w1 + j);
    s1 = fma((double)xv.x, (double)av.x, s1); s1 = fma((double)xv.y, (double)av.y, s1);
    s1 = fma((double)xv.z, (double)av.z, s1); s1 = fma((double)xv.w, (double)av.w, s1);
    av = *(const float4*)(w2 + j);
    s2 = fma((double)xv.x, (double)av.x, s2); s2 = fma((double)xv.y, (double)av.y, s2);
    s2 = fma((double)xv.z, (double)av.z, s2); s2 = fma((double)xv.w, (double)av.w, s2);
    av = *(const float4*)(w3 + j);
    s3 = fma((double)xv.x, (double)av.x, s3); s3 = fma((double)xv.y, (double)av.y, s3);
    s3 = fma((double)xv.z, (double)av.z, s3); s3 = fma((double)xv.w, (double)av.w, s3);
  }
#pragma unroll
  for (int m = 1; m < 64; m <<= 1) {
    s0 += __shfl_xor(s0, m);
    s1 += __shfl_xor(s1, m);
    s2 += __shfl_xor(s2, m);
    s3 += __shfl_xor(s3, m);
  }
  if (l == 0) {
    double v0 = s0, v1 = s1, v2 = s2, v3 = s3;
    int i0 = e0, i1 = e1, i2 = e2, i3 = e3;
    if (betterd(v1, i1, v0, i0)) { double tv = v0; v0 = v1; v1 = tv; int ti = i0; i0 = i1; i1 = ti; }
    if (betterd(v3, i3, v2, i2)) { double tv = v2; v2 = v3; v3 = tv; int ti = i2; i2 = i3; i3 = ti; }
    if (betterd(v2, i2, v0, i0)) { double tv = v0; v0 = v2; v2 = tv; int ti = i0; i0 = i2; i2 = ti; }
    if (betterd(v3, i3, v1, i1)) { double tv = v1; v1 = v3; v3 = tv; int ti = i1; i1 = i3; i3 = ti; }
    if (betterd(v2, i2, v1, i1)) { double tv = v1; v1 = v2; v2 = tv; int ti = i1; i1 = i2; i2 = ti; }
    double ex = exp(v1 - v0);
    double den = 1.0 + ex;
    out_idx[tok * 2 + 0] = (float)i0;
    out_idx[tok * 2 + 1] = (float)i1;
    out_wt[tok * 2 + 0]  = (float)(1.0 / den);
    out_wt[tok * 2 + 1]  = (float)(ex / den);
  }
}

// ---- kernel 2: cooperative double-buffered tile, 1KiB-contiguous X staging ----
// 512 blocks x 256 thr (4 waves). Block = 32 tokens x 64 experts x full K.
// LDS: 2 x [32 rows][1 KiB] = 64 KiB (T2-swizzled), aliased as Lg[32][68] in epilogue.
__global__ __launch_bounds__(256, 2)
void router_main(const float* __restrict__ x, const float* __restrict__ wgt,
                 const short* __restrict__ ws, float* __restrict__ out) {
  __shared__ __align__(16) char ldsbuf[65536];

  const int u = threadIdx.x;
  const int l = u & 63;
  const int wid = u >> 6;          // wave 0..3
  const int tokBase = blockIdx.x * 32;
  const int hq = l >> 4;           // k-quarter within fragment

  // ---- staging geometry: wave wid stages rows wid*8 .. wid*8+7 ----
  // row r (r&7 == j compile-time): global source pre-swizzled by ((j&7)<<4) bytes,
  // LDS dest linear at row*1024. (rule #21: linear dest + inv-swz source + swz read)
  const float* xsrc = x + (size_t)(tokBase + wid * 8) * DDIM;
  const int l4 = l * 4;            // lane float-offset within the 1 KiB row

#define STAGE(B, T)                                                            \
  {                                                                            \
    char* bb = ldsbuf + (B) * 32768 + wid * 8192;                              \
    const float* xs = xsrc + (T) * KSTEP;                                      \
    gld_lds16(xs + 0 * DDIM + (l4 ^  0), bb + 0 * 1024);                       \
    gld_lds16(xs + 1 * DDIM + (l4 ^  4), bb + 1 * 1024);                       \
    gld_lds16(xs + 2 * DDIM + (l4 ^  8), bb + 2 * 1024);                       \
    gld_lds16(xs + 3 * DDIM + (l4 ^ 12), bb + 3 * 1024);                       \
    gld_lds16(xs + 4 * DDIM + (l4 ^ 16), bb + 4 * 1024);                       \
    gld_lds16(xs + 5 * DDIM + (l4 ^ 20), bb + 5 * 1024);                       \
    gld_lds16(xs + 6 * DDIM + (l4 ^ 24), bb + 6 * 1024);                       \
    gld_lds16(xs + 7 * DDIM + (l4 ^ 28), bb + 7 * 1024);                       \
  }

  // ---- compute geometry: wave wid owns token-tile tt=wid&1, experts (wid>>1)*32.. ----
  const int tt  = wid & 1;
  const int egA = (wid >> 1) * 2;            // expert groups egA, egA+1
  const int row = tt * 16 + (l & 15);
  const int sw  = (l & 7) << 4;              // T2 XOR swizzle (bytes)
  const int a0c = ((hq * 32) ^ sw);          // per-lane base offsets within row
  const int a1c = ((hq * 32 + 16) ^ sw);
  const short* whp = ws + l * 8;

  f32x4 accA = {0.f, 0.f, 0.f, 0.f};
  f32x4 accB = {0.f, 0.f, 0.f, 0.f};

#define COMPUTE(B, T)                                                          \
  {                                                                            \
    const char* arow = ldsbuf + (B) * 32768 + row * 1024;                      \
    const char* arow0 = arow + a0c;                                            \
    const char* arow1 = arow + a1c;                                            \
    _Pragma("unroll")                                                          \
    for (int ks = 0; ks < 8; ++ks) {                                           \
      float4 f0 = *(const float4*)(arow0 + ks * 128);                          \
      float4 f1 = *(const float4*)(arow1 + ks * 128);                          \
      uint2 h0, s0, h1, s1;                                                    \
      split4(f0, h0, s0); split4(f1, h1, s1);                                  \
      bf16x8 ahi = mk8(h0, h1), alo = mk8(s0, s1);                             \
      const int cc = (T) * 8 + ks;                                             \
      bf16x8 wAh = *(const bf16x8*)(whp + cc * 2048 + egA * 512);              \
      bf16x8 wAl = *(const bf16x8*)(whp + WS_LO + cc * 2048 + egA * 512);      \
      bf16x8 wBh = *(const bf16x8*)(whp + cc * 2048 + (egA + 1) * 512);        \
      bf16x8 wBl = *(const bf16x8*)(whp + WS_LO + cc * 2048 + (egA + 1) * 512);\
      accA = __builtin_amdgcn_mfma_f32_16x16x32_bf16(ahi, wAh, accA, 0, 0, 0); \
      accB = __builtin_amdgcn_mfma_f32_16x16x32_bf16(ahi, wBh, accB, 0, 0, 0); \
      accA = __builtin_amdgcn_mfma_f32_16x16x32_bf16(ahi, wAl, accA, 0, 0, 0); \
      accB = __builtin_amdgcn_mfma_f32_16x16x32_bf16(ahi, wBl, accB, 0, 0, 0); \
      accA = __builtin_amdgcn_mfma_f32_16x16x32_bf16(alo, wAh, accA, 0, 0, 0); \
      accB = __builtin_amdgcn_mfma_f32_16x16x32_bf16(alo, wBh, accB, 0, 0, 0); \
    }                                                                          \
  }

  // ---- main loop: 2-phase double buffer, stage(t+1) before compute(t) ----
  STAGE(0, 0)
  __syncthreads();               // compiler drains vmcnt(0) before s_barrier
  for (int t = 0; t < NSTEP; ++t) {
    if (t + 1 < NSTEP) STAGE((t + 1) & 1, t + 1)
    asm volatile("" ::: "memory");   // pin: issue stage loads before compute
    COMPUTE(t & 1, t)
    __syncthreads();
  }

  // ---- epilogue: logits tile -> LDS (aliased), then top-2 ----
  __syncthreads();               // all reads of ldsbuf done; safe to alias
  float* Lg = (float*)ldsbuf;    // [32][68]
  {
    const int trow = tt * 16 + (l >> 4) * 4;
    const int colA = egA * 16 + (l & 15);
#pragma unroll
    for (int r = 0; r < 4; ++r) {
      Lg[(trow + r) * 68 + colA]      = accA[r];
      Lg[(trow + r) * 68 + colA + 16] = accB[r];
    }
  }
  __syncthreads();

  float* out_idx = out;
  float* out_wt  = out + NTOK * 2;
  float* out_lg  = out + NTOK * 4;

  // 8 threads per token: top-4 of 64 + flag near-ties
  {
    const int t = u >> 3;        // token row 0..31
    const int p = u & 7;
    float4 q0 = *(const float4*)&Lg[t * 68 + p * 8];
    float4 q1 = *(const float4*)&Lg[t * 68 + p * 8 + 4];

    float* dst = out_lg + (size_t)(tokBase + t) * NEXP + p * 8;
    *(float4*)dst = q0;
    *(float4*)(dst + 4) = q1;

    int base = p * 8;
    float a0 = q0.x, a1 = q0.y, a2 = q0.z, a3 = q0.w;
    int   ia0 = base, ia1 = base + 1, ia2 = base + 2, ia3 = base + 3;
    float b0 = q1.x, b1 = q1.y, b2 = q1.z, b3 = q1.w;
    int   ib0 = base + 4, ib1 = base + 5, ib2 = base + 6, ib3 = base + 7;
    CE(a0, ia0, a1, ia1) CE(a2, ia2, a3, ia3) CE(a0, ia0, a2, ia2) CE(a1, ia1, a3, ia3) CE(a1, ia1, a2, ia2)
    CE(b0, ib0, b1, ib1) CE(b2, ib2, b3, ib3) CE(b0, ib0, b2, ib2) CE(b1, ib1, b3, ib3) CE(b1, ib1, b2, ib2)
    CE(a0, ia0, b3, ib3) CE(a1, ia1, b2, ib2) CE(a2, ia2, b1, ib1) CE(a3, ia3, b0, ib0)
    CE(a0, ia0, a2, ia2) CE(a1, ia1, a3, ia3) CE(a0, ia0, a1, ia1) CE(a2, ia2, a3, ia3)

#pragma unroll
    for (int m = 1; m <= 4; m <<= 1) {
      float p0 = __shfl_xor(a0, m), p1 = __shfl_xor(a1, m);
      float p2 = __shfl_xor(a2, m), p3 = __shfl_xor(a3, m);
      int j0 = __shfl_xor(ia0, m), j1 = __shfl_xor(ia1, m);
      int j2 = __shfl_xor(ia2, m), j3 = __shfl_xor(ia3, m);
      CE(a0, ia0, p3, j3) CE(a1, ia1, p2, j2) CE(a2, ia2, p1, j1) CE(a3, ia3, p0, j0)
      CE(a0, ia0, a2, ia2) CE(a1, ia1, a3, ia3) CE(a0, ia0, a1, ia1) CE(a2, ia2, a3, ia3)
    }

    bool flag = false;
    unsigned pk = 0;
    if (p == 0) {
      flag = (a0 - a1 < TAU) || (a1 - a2 < TAU) || (a2 - a3 < TAU);
      pk = (unsigned)ia0 | ((unsigned)ia1 << 8) | ((unsigned)ia2 << 16) | ((unsigned)ia3 << 24);
      if (!flag) {
        const int tok = tokBase + t;
        float ex = expf(a1 - a0);
        float den = 1.0f + ex;
        out_idx[tok * 2 + 0] = (float)ia0;
        out_idx[tok * 2 + 1] = (float)ia1;
        out_wt[tok * 2 + 0]  = 1.0f / den;
        out_wt[tok * 2 + 1]  = ex / den;
      }
    }
    unsigned long long mk = __ballot(flag);
    while (mk) {
      const int src = __builtin_ctzll(mk);
      mk &= mk - 1;
      const unsigned pks = (unsigned)__shfl((int)pk, src);
      fixup_token(x, wgt, out_idx, out_wt, tokBase + wid * 8 + (src >> 3), pks, l);
    }
  }
}

extern "C" void kernel_launch(void* const* d_in, const int* in_sizes, int n_in,
                              void* d_out, int out_size, void* d_ws, size_t ws_size,
                              hipStream_t stream) {
  const float* x = (const float*)d_in[0];   // [4,4096,4096] f32
  const float* w = (const float*)d_in[1];   // [64,4096] f32
  float* out = (float*)d_out;               // 32768 idx + 32768 wt + 1048576 logits (all f32)
  short* ws = (short*)d_ws;                 // 1 MiB: bf16 hi/lo planes of W

  hipLaunchKernelGGL(presplit_w, dim3(128), dim3(256), 0, stream, w, ws);
  hipLaunchKernelGGL(router_main, dim3(NTOK / 32), dim3(256), 0, stream, x, w, ws, out);
}

// Round 7
// 85.853 us; speedup vs baseline: 1.2690x; 1.2690x over previous
//
#include <hip/hip_runtime.h>
#include <math.h>

#define NTOK 16384
#define DDIM 4096
#define NEXP 64
#define TAU  2e-4f
#define WS_LO 262144   // short-offset of the lo-plane inside d_ws
#define NCW  32        // chunks per K-quarter (1024 k / 32)

typedef short bf16x8 __attribute__((ext_vector_type(8)));
typedef float f32x4  __attribute__((ext_vector_type(4)));

__device__ __forceinline__ unsigned short bf16_rne(float f) {
  unsigned u = __float_as_uint(f);
  u += 0x7fffu + ((u >> 16) & 1u);
  return (unsigned short)(u >> 16);
}

__device__ __forceinline__ void split4(float4 v, uint2& hi, uint2& lo) {
  unsigned h0 = bf16_rne(v.x), h1 = bf16_rne(v.y), h2 = bf16_rne(v.z), h3 = bf16_rne(v.w);
  float r0 = v.x - __uint_as_float(h0 << 16);
  float r1 = v.y - __uint_as_float(h1 << 16);
  float r2 = v.z - __uint_as_float(h2 << 16);
  float r3 = v.w - __uint_as_float(h3 << 16);
  unsigned l0 = bf16_rne(r0), l1 = bf16_rne(r1), l2 = bf16_rne(r2), l3 = bf16_rne(r3);
  hi = make_uint2(h0 | (h1 << 16), h2 | (h3 << 16));
  lo = make_uint2(l0 | (l1 << 16), l2 | (l3 << 16));
}

__device__ __forceinline__ bf16x8 mk8(uint2 a, uint2 b) {
  union { uint4 u; bf16x8 v; } t;
  t.u = make_uint4(a.x, a.y, b.x, b.y);
  return t.v;
}

__device__ __forceinline__ void gld_lds16(const float* g, char* l) {
  __builtin_amdgcn_global_load_lds((const __attribute__((address_space(1))) void*)g,
                                   (__attribute__((address_space(3))) void*)l,
                                   16, 0, 0);
}

__device__ __forceinline__ bool better(float va, int ia, float vb, int ib) {
  return (va > vb) || (va == vb && ia < ib);
}
__device__ __forceinline__ bool betterd(double va, int ia, double vb, int ib) {
  return (va > vb) || (va == vb && ia < ib);
}
#define CE(va, ia, vb, ib) { if (better(vb, ib, va, ia)) { float _tv = va; va = vb; vb = _tv; int _ti = ia; ia = ib; ib = _ti; } }

// ---- kernel 1: split W (fp32) into bf16 hi/lo, MFMA-fragment-linear, once ----
__global__ __launch_bounds__(256)
void presplit_w(const float* __restrict__ w, short* __restrict__ ws) {
  const int tid = blockIdx.x * 256 + threadIdx.x;  // 32768 threads
  const int e = tid >> 9;          // expert 0..63
  const int o = tid & 511;         // k-octet 0..511
  const int c = o >> 2, q = o & 3;
  const int l = (e & 15) + 16 * q;
  const int g = e >> 4;
  const float* src = w + (size_t)e * DDIM + o * 8;
  float4 v0 = *(const float4*)src;
  float4 v1 = *(const float4*)(src + 4);
  uint2 h0, s0, h1, s1;
  split4(v0, h0, s0);
  split4(v1, h1, s1);
  const int off = c * 2048 + g * 512 + l * 8;
  *(uint4*)(ws + off)         = make_uint4(h0.x, h0.y, h1.x, h1.y);
  *(uint4*)(ws + WS_LO + off) = make_uint4(s0.x, s0.y, s1.x, s1.y);
}

// ---- fp64 recompute for near-tie tokens (rare); executed by one full wave ----
__device__ __noinline__ void fixup_token(const float* __restrict__ x,
                                         const float* __restrict__ wgt,
                                         float* __restrict__ out_idx,
                                         float* __restrict__ out_wt,
                                         int tok, unsigned pk, int l) {
  const int e0 = pk & 255, e1 = (pk >> 8) & 255, e2 = (pk >> 16) & 255, e3 = (pk >> 24) & 255;
  const float* xr = x   + (size_t)tok * DDIM + l * 64;
  const float* w0 = wgt + (size_t)e0 * DDIM + l * 64;
  const float* w1 = wgt + (size_t)e1 * DDIM + l * 64;
  const float* w2 = wgt + (size_t)e2 * DDIM + l * 64;
  const float* w3 = wgt + (size_t)e3 * DDIM + l * 64;
  double s0 = 0.0, s1 = 0.0, s2 = 0.0, s3 = 0.0;
#pragma unroll 4
  for (int j = 0; j < 64; j += 4) {
    float4 xv = *(const float4*)(xr + j);
    float4 av = *(const float4*)(w0 + j);
    s0 = fma((double)xv.x, (double)av.x, s0); s0 = fma((double)xv.y, (double)av.y, s0);
    s0 = fma((double)xv.z, (double)av.z, s0); s0 = fma((double)xv.w, (double)av.w, s0);
    av = *(const float4*)(w1 + j);
    s1 = fma((double)xv.x, (double)av.x, s1); s1 = fma((double)xv.y, (double)av.y, s1);
    s1 = fma((double)xv.z, (double)av.z, s1); s1 = fma((double)xv.w, (double)av.w, s1);
    av = *(const float4*)(w2 + j);
    s2 = fma((double)xv.x, (double)av.x, s2); s2 = fma((double)xv.y, (double)av.y, s2);
    s2 = fma((double)xv.z, (double)av.z, s2); s2 = fma((double)xv.w, (double)av.w, s2);
    av = *(const float4*)(w3 + j);
    s3 = fma((double)xv.x, (double)av.x, s3); s3 = fma((double)xv.y, (double)av.y, s3);
    s3 = fma((double)xv.z, (double)av.z, s3); s3 = fma((double)xv.w, (double)av.w, s3);
  }
#pragma unroll
  for (int m = 1; m < 64; m <<= 1) {
    s0 += __shfl_xor(s0, m);
    s1 += __shfl_xor(s1, m);
    s2 += __shfl_xor(s2, m);
    s3 += __shfl_xor(s3, m);
  }
  if (l == 0) {
    double v0 = s0, v1 = s1, v2 = s2, v3 = s3;
    int i0 = e0, i1 = e1, i2 = e2, i3 = e3;
    if (betterd(v1, i1, v0, i0)) { double tv = v0; v0 = v1; v1 = tv; int ti = i0; i0 = i1; i1 = ti; }
    if (betterd(v3, i3, v2, i2)) { double tv = v2; v2 = v3; v3 = tv; int ti = i2; i2 = i3; i3 = ti; }
    if (betterd(v2, i2, v0, i0)) { double tv = v0; v0 = v2; v2 = tv; int ti = i0; i0 = i2; i2 = ti; }
    if (betterd(v3, i3, v1, i1)) { double tv = v1; v1 = v3; v3 = tv; int ti = i1; i1 = i3; i3 = ti; }
    if (betterd(v2, i2, v1, i1)) { double tv = v1; v1 = v2; v2 = tv; int ti = i1; i1 = i2; i2 = ti; }
    double ex = exp(v1 - v0);
    double den = 1.0 + ex;
    out_idx[tok * 2 + 0] = (float)i0;
    out_idx[tok * 2 + 1] = (float)i1;
    out_wt[tok * 2 + 0]  = (float)(1.0 / den);
    out_wt[tok * 2 + 1]  = (float)(ex / den);
  }
}

// ---- kernel 2: barrier-free main loop, deep counted-vmcnt pipeline ----
// 512 blocks x 256 thr (4 waves = 4 K-quarters). Block = 32 tokens x 64 experts.
// Per wave: 4-slot X ring (4 KB/slot), X issued 3 chunks ahead, W quad-buffered
// in regs issued 3 chunks ahead. Uniform s_waitcnt vmcnt(28): X(t),W(t) landed,
// X(t+1..t+3)=12KB/wave stays airborne. Per-block k-phase rotation spreads
// co-resident blocks across DRAM channels (16KiB row stride aliasing fix).
__global__ __launch_bounds__(256, 2)
void router_main(const float* __restrict__ x, const float* __restrict__ wgt,
                 const short* __restrict__ ws, float* __restrict__ out) {
  __shared__ __align__(16) char ldsbuf[65536];

  const int u = threadIdx.x;
  const int l = u & 63;
  const int wid = u >> 6;          // K-quarter 0..3
  const int tokBase = blockIdx.x * 32;
  const int row = l & 15;
  const int hq = l >> 4;

  char* ring = ldsbuf + wid * 16384;   // 4 slots x 4096 B

  // k-phase rotation: block-local chunk t reads physical chunk (t+P)&31
  const int P = (blockIdx.x * 13) & 31;
#define PHYS(T) (((T) + P) & 31)

  // per-lane global X sources (tile tt = j>>1, k-half = j&1), as round 5
  const float* xb0 = x + (size_t)(tokBase +  0 + row) * DDIM + wid * 1024 +  0 + hq * 4;
  const float* xb1 = x + (size_t)(tokBase +  0 + row) * DDIM + wid * 1024 + 16 + hq * 4;
  const float* xb2 = x + (size_t)(tokBase + 16 + row) * DDIM + wid * 1024 +  0 + hq * 4;
  const float* xb3 = x + (size_t)(tokBase + 16 + row) * DDIM + wid * 1024 + 16 + hq * 4;

  const short* whp = ws + wid * 65536 + l * 8;

  // A-fragment byte offset inside a (slot, tt) 2 KB block
  const int dsoff = (hq >> 1) * 1024 + ((hq & 1) * 32 + row) * 16;

  f32x4 acc[2][4];
#pragma unroll
  for (int tt = 0; tt < 2; ++tt)
#pragma unroll
    for (int g = 0; g < 4; ++g) acc[tt][g] = (f32x4){0.f, 0.f, 0.f, 0.f};

  bf16x8 wh0[4], wl0[4], wh1[4], wl1[4], wh2[4], wl2[4], wh3[4], wl3[4];

#define LDW(WH, WL, T)                                                         \
  { const int cc_ = PHYS(T);                                                   \
    _Pragma("unroll")                                                          \
    for (int g = 0; g < 4; ++g) {                                              \
      WH[g] = *(const bf16x8*)(whp + cc_ * 2048 + g * 512);                    \
      WL[g] = *(const bf16x8*)(whp + WS_LO + cc_ * 2048 + g * 512);            \
    } }

#define XISSUE(T, SLOT)                                                        \
  { const int xo_ = PHYS(T) * 32;                                              \
    char* xd_ = ring + (SLOT) * 4096;                                          \
    gld_lds16(xb0 + xo_, xd_);                                                 \
    gld_lds16(xb1 + xo_, xd_ + 1024);                                          \
    gld_lds16(xb2 + xo_, xd_ + 2048);                                          \
    gld_lds16(xb3 + xo_, xd_ + 3072); }

  // prologue FIFO: X0,W0,X1,W1,X2,W2  (order pinned by memory-clobber asm)
  XISSUE(0, 0)
  asm volatile("" ::: "memory");
  LDW(wh0, wl0, 0)
  asm volatile("" ::: "memory");
  XISSUE(1, 1)
  asm volatile("" ::: "memory");
  LDW(wh1, wl1, 1)
  asm volatile("" ::: "memory");
  XISSUE(2, 2)
  asm volatile("" ::: "memory");
  LDW(wh2, wl2, 2)

  // per step T (consume slot/set T&3, issue X(T+3)->slot (T+3)&3, W(T+3)->set (T+3)&3):
  // FIFO at wait: X(T),W(T) | X(T+1),W(T+1),X(T+2),W(T+2),X(T+3) = 28 newer than W(T).
  // Tail (T+3 >= 32): PHYS wraps to an already-read chunk; dest slot/set is dead. Uniform counts.
#define STEP(T, SR, SW, WHc, WLc, WHn, WLn)                                    \
  {                                                                            \
    asm volatile("" ::: "memory");                                             \
    XISSUE((T) + 3, SW)                                                        \
    asm volatile("s_waitcnt vmcnt(28)" ::: "memory");                          \
    const char* rb = ring + (SR) * 4096;                                       \
    {                                                                          \
      float4 f0 = *(const float4*)(rb + dsoff);                                \
      float4 f1 = *(const float4*)(rb + dsoff + 256);                          \
      uint2 h0, s0, h1, s1;                                                    \
      split4(f0, h0, s0); split4(f1, h1, s1);                                  \
      bf16x8 ahi = mk8(h0, h1), alo = mk8(s0, s1);                             \
      _Pragma("unroll")                                                        \
      for (int g = 0; g < 4; ++g) {                                            \
        acc[0][g] = __builtin_amdgcn_mfma_f32_16x16x32_bf16(ahi, WHc[g], acc[0][g], 0, 0, 0); \
        acc[0][g] = __builtin_amdgcn_mfma_f32_16x16x32_bf16(ahi, WLc[g], acc[0][g], 0, 0, 0); \
        acc[0][g] = __builtin_amdgcn_mfma_f32_16x16x32_bf16(alo, WHc[g], acc[0][g], 0, 0, 0); \
      }                                                                        \
    }                                                                          \
    {                                                                          \
      float4 f0 = *(const float4*)(rb + 2048 + dsoff);                         \
      float4 f1 = *(const float4*)(rb + 2048 + dsoff + 256);                   \
      uint2 h0, s0, h1, s1;                                                    \
      split4(f0, h0, s0); split4(f1, h1, s1);                                  \
      bf16x8 ahi = mk8(h0, h1), alo = mk8(s0, s1);                             \
      _Pragma("unroll")                                                        \
      for (int g = 0; g < 4; ++g) {                                            \
        acc[1][g] = __builtin_amdgcn_mfma_f32_16x16x32_bf16(ahi, WHc[g], acc[1][g], 0, 0, 0); \
        acc[1][g] = __builtin_amdgcn_mfma_f32_16x16x32_bf16(ahi, WLc[g], acc[1][g], 0, 0, 0); \
        acc[1][g] = __builtin_amdgcn_mfma_f32_16x16x32_bf16(alo, WHc[g], acc[1][g], 0, 0, 0); \
      }                                                                        \
    }                                                                          \
    asm volatile("" ::: "memory");                                             \
    LDW(WHn, WLn, (T) + 3)                                                     \
  }

  for (int t = 0; t < NCW; t += 4) {
    STEP(t + 0, 0, 3, wh0, wl0, wh3, wl3)
    STEP(t + 1, 1, 0, wh1, wl1, wh0, wl0)
    STEP(t + 2, 2, 1, wh2, wl2, wh1, wl1)
    STEP(t + 3, 3, 2, wh3, wl3, wh2, wl2)
  }

  // ---- combine K-quarters through LDS (aliased over the ring) ----
  __syncthreads();   // drains vmcnt(0): all (dummy) gld_lds landed; rings dead
  float* p = (float*)ldsbuf;
#define PIDX(KQ, TT, G, R) ((((((KQ) * 2 + (TT)) * 4 + (G)) * 4 + (R)) << 6) + l)
#pragma unroll
  for (int tt = 0; tt < 2; ++tt)
#pragma unroll
    for (int g = 0; g < 4; ++g)
#pragma unroll
      for (int r = 0; r < 4; ++r)
        p[PIDX(wid, tt, g, r)] = acc[tt][g][r];
  __syncthreads();

  float* out_idx = out;
  float* out_wt  = out + NTOK * 2;
  float* out_lg  = out + NTOK * 4;

  // wave `wid` handles accumulator row r = wid, for both token tiles
#pragma unroll
  for (int tt = 0; tt < 2; ++tt) {
    float v0 = p[PIDX(0, tt, 0, wid)] + p[PIDX(1, tt, 0, wid)] + p[PIDX(2, tt, 0, wid)] + p[PIDX(3, tt, 0, wid)];
    float v1 = p[PIDX(0, tt, 1, wid)] + p[PIDX(1, tt, 1, wid)] + p[PIDX(2, tt, 1, wid)] + p[PIDX(3, tt, 1, wid)];
    float v2 = p[PIDX(0, tt, 2, wid)] + p[PIDX(1, tt, 2, wid)] + p[PIDX(2, tt, 2, wid)] + p[PIDX(3, tt, 2, wid)];
    float v3 = p[PIDX(0, tt, 3, wid)] + p[PIDX(1, tt, 3, wid)] + p[PIDX(2, tt, 3, wid)] + p[PIDX(3, tt, 3, wid)];

    const int tok = tokBase + tt * 16 + (l >> 4) * 4 + wid;
    {
      float* dst = out_lg + (size_t)tok * NEXP + (l & 15);
      dst[0]  = v0;
      dst[16] = v1;
      dst[32] = v2;
      dst[48] = v3;
    }

    const int cbase = (l & 15);
    int i0 = cbase, i1 = cbase + 16, i2 = cbase + 32, i3 = cbase + 48;
    CE(v0, i0, v1, i1) CE(v2, i2, v3, i3) CE(v0, i0, v2, i2) CE(v1, i1, v3, i3) CE(v1, i1, v2, i2)
#pragma unroll
    for (int m = 1; m <= 8; m <<= 1) {
      float p0 = __shfl_xor(v0, m), p1 = __shfl_xor(v1, m);
      float p2 = __shfl_xor(v2, m), p3 = __shfl_xor(v3, m);
      int j0 = __shfl_xor(i0, m), j1 = __shfl_xor(i1, m);
      int j2 = __shfl_xor(i2, m), j3 = __shfl_xor(i3, m);
      CE(v0, i0, p3, j3) CE(v1, i1, p2, j2) CE(v2, i2, p1, j1) CE(v3, i3, p0, j0)
      CE(v0, i0, v2, i2) CE(v1, i1, v3, i3) CE(v0, i0, v1, i1) CE(v2, i2, v3, i3)
    }

    bool flag = false;
    unsigned pk = 0;
    if (cbase == 0) {
      flag = (v0 - v1 < TAU) || (v1 - v2 < TAU) || (v2 - v3 < TAU);
      pk = (unsigned)i0 | ((unsigned)i1 << 8) | ((unsigned)i2 << 16) | ((unsigned)i3 << 24);
      if (!flag) {
        float ex = expf(v1 - v0);
        float den = 1.0f + ex;
        out_idx[tok * 2 + 0] = (float)i0;
        out_idx[tok * 2 + 1] = (float)i1;
        out_wt[tok * 2 + 0]  = 1.0f / den;
        out_wt[tok * 2 + 1]  = ex / den;
      }
    }
    unsigned long long mk = __ballot(flag);
    while (mk) {
      const int src = __builtin_ctzll(mk);
      mk &= mk - 1;
      const unsigned pks = (unsigned)__shfl((int)pk, src);
      fixup_token(x, wgt, out_idx, out_wt, tokBase + tt * 16 + (src >> 4) * 4 + wid, pks, l);
    }
  }
}

extern "C" void kernel_launch(void* const* d_in, const int* in_sizes, int n_in,
                              void* d_out, int out_size, void* d_ws, size_t ws_size,
                              hipStream_t stream) {
  const float* x = (const float*)d_in[0];   // [4,4096,4096] f32
  const float* w = (const float*)d_in[1];   // [64,4096] f32
  float* out = (float*)d_out;               // 32768 idx + 32768 wt + 1048576 logits (all f32)
  short* ws = (short*)d_ws;                 // 1 MiB: bf16 hi/lo planes of W

  hipLaunchKernelGGL(presplit_w, dim3(128), dim3(256), 0, stream, w, ws);
  hipLaunchKernelGGL(router_main, dim3(NTOK / 32), dim3(256), 0, stream, x, w, ws, out);
}